// Round 3
// baseline (101.921 us; speedup 1.0000x reference)
//
#include <hip/hip_runtime.h>
#include <hip/hip_bf16.h>

typedef __bf16 bf16_t;
typedef __bf16 bf16x4 __attribute__((ext_vector_type(4)));
typedef __bf16 bf16x8 __attribute__((ext_vector_type(8)));
typedef float f32x4 __attribute__((ext_vector_type(4)));

#define BATCH 128
#define NS 512
#define DIM 256
#define BT 128    // output tile (M = N = 128)
#define NTILES_SYM 10

// =================== fast path (bf16 pre-converted) ===================

// Kernel A: fused convert fp32->bf16 + row norms. One wave per row (256 f32).
__global__ __launch_bounds__(256) void conv_norms_kernel(const float* __restrict__ dv,
                                                         bf16_t* __restrict__ dvh,
                                                         float* __restrict__ n2) {
    const int row  = blockIdx.x * 4 + (threadIdx.x >> 6);
    const int lane = threadIdx.x & 63;
    const float4 v = *reinterpret_cast<const float4*>(dv + (size_t)row * DIM + lane * 4);
    bf16x4 hv = { (bf16_t)v.x, (bf16_t)v.y, (bf16_t)v.z, (bf16_t)v.w };
    *reinterpret_cast<bf16x4*>(dvh + (size_t)row * DIM + lane * 4) = hv;
    float s = v.x * v.x + v.y * v.y + v.z * v.z + v.w * v.w;
#pragma unroll
    for (int off = 32; off >= 1; off >>= 1) s += __shfl_down(s, off, 64);
    if (lane == 0) n2[row] = s;
}

// Kernel B: St = S^T (LDS 32x33 tiles) fused with denom partials ||W-I||_F^2.
// grid 256 blocks (16x16 tiles), 256 threads.
__global__ __launch_bounds__(256) void st_denom_kernel(const float* __restrict__ S,
                                                       float* __restrict__ St,
                                                       float* __restrict__ dpartial) {
    const int bi = blockIdx.x >> 4, bj = blockIdx.x & 15;
    const int t  = threadIdx.x;
    const int c  = t & 31, r0 = t >> 5;
    __shared__ float tileS[32][33];
    __shared__ float red[4];
    float dacc = 0.0f;
#pragma unroll
    for (int k = 0; k < 4; ++k) {
        const int r  = r0 + k * 8;
        const int gi = bi * 32 + r, gj = bj * 32 + c;
        const float s = S[(size_t)gi * NS + gj];
        tileS[r][c] = s;
        const float w = (s > 0.0f) ? 1.0f : 0.0f;
        const float e = (gi == gj) ? 1.0f : 0.0f;
        const float d = w - e;
        dacc += d * d;
    }
    __syncthreads();
#pragma unroll
    for (int k = 0; k < 4; ++k) {
        const int r = r0 + k * 8;
        St[(size_t)(bj * 32 + r) * NS + bi * 32 + c] = tileS[c][r];
    }
    const int lane = t & 63, wave = t >> 6;
#pragma unroll
    for (int off = 32; off >= 1; off >>= 1) dacc += __shfl_down(dacc, off, 64);
    if (lane == 0) red[wave] = dacc;
    __syncthreads();
    if (t == 0) dpartial[blockIdx.x] = red[0] + red[1] + red[2] + red[3];
}

// Kernel C: symmetric batched Gram + fused epilogue.
// grid (10, BATCH); 256 threads = 4 waves (2x2), each wave owns 64x64.
#define BK 64
#define LDSK 72   // padded k-stride (144 B rows): 2-way bank aliasing only (free)
__global__ __launch_bounds__(256) void gram_bf16_kernel(const bf16_t* __restrict__ dvh,
                                                        const float* __restrict__ S,
                                                        const float* __restrict__ St,
                                                        const float* __restrict__ n2,
                                                        float* __restrict__ partial) {
    const int idx = blockIdx.x;  // 0..9 upper-triangular tile enumeration
    int ti, tj;
    if (idx < 4)      { ti = 0; tj = idx; }
    else if (idx < 7) { ti = 1; tj = idx - 3; }
    else if (idx < 9) { ti = 2; tj = idx - 5; }
    else              { ti = 3; tj = 3; }
    const bool diag = (ti == tj);
    const int b    = blockIdx.y;
    const int t    = threadIdx.x;
    const int wave = t >> 6, lane = t & 63;
    const int wr   = wave >> 1, wc = wave & 1;

    __shared__ bf16_t sA[BT * LDSK];
    __shared__ bf16_t sB[BT * LDSK];
    __shared__ float red[4];

    const bf16_t* Abase = dvh + ((size_t)b * NS + (size_t)ti * BT) * DIM;
    const bf16_t* Bbase = dvh + ((size_t)b * NS + (size_t)tj * BT) * DIM;

    f32x4 acc[4][4];
#pragma unroll
    for (int m = 0; m < 4; ++m)
#pragma unroll
        for (int n = 0; n < 4; ++n) acc[m][n] = (f32x4)(0.0f);

    const int fr = lane & 15;   // fragment row within 16
    const int g  = lane >> 4;   // k-group (8 consecutive k)

    for (int ks = 0; ks < DIM; ks += BK) {
        // stage 128 rows x 64 k bf16 per tile; per thread 4 x 16B per tile
        bf16x8 ra[4], rb[4];
#pragma unroll
        for (int i = 0; i < 4; ++i) {
            const int c   = i * 256 + t;
            const int row = c >> 3;
            const int kc  = (c & 7) * 8;
            ra[i] = *reinterpret_cast<const bf16x8*>(Abase + (size_t)row * DIM + ks + kc);
            if (!diag) rb[i] = *reinterpret_cast<const bf16x8*>(Bbase + (size_t)row * DIM + ks + kc);
        }
        __syncthreads();  // previous compute done reading LDS
#pragma unroll
        for (int i = 0; i < 4; ++i) {
            const int c   = i * 256 + t;
            const int row = c >> 3;
            const int kc  = (c & 7) * 8;
            *reinterpret_cast<bf16x8*>(&sA[row * LDSK + kc]) = ra[i];
            if (!diag) *reinterpret_cast<bf16x8*>(&sB[row * LDSK + kc]) = rb[i];
        }
        __syncthreads();  // writes visible

        const bf16_t* sBp = diag ? sA : sB;
#pragma unroll
        for (int h = 0; h < 2; ++h) {
            bf16x8 afrag[4], bfrag[4];
#pragma unroll
            for (int m = 0; m < 4; ++m)
                afrag[m] = *reinterpret_cast<const bf16x8*>(&sA[(wr * 64 + m * 16 + fr) * LDSK + h * 32 + g * 8]);
#pragma unroll
            for (int n = 0; n < 4; ++n)
                bfrag[n] = *reinterpret_cast<const bf16x8*>(&sBp[(wc * 64 + n * 16 + fr) * LDSK + h * 32 + g * 8]);
#pragma unroll
            for (int m = 0; m < 4; ++m)
#pragma unroll
                for (int n = 0; n < 4; ++n)
                    acc[m][n] = __builtin_amdgcn_mfma_f32_16x16x32_bf16(afrag[m], bfrag[n], acc[m][n], 0, 0, 0);
        }
    }

    // epilogue: C/D layout col = lane&15, row = (lane>>4)*4 + j [guide-verified]
    float local = 0.0f;
    const float* n2b = n2 + (size_t)b * NS;
    const int rowbase = ti * BT + wr * 64;
    const int colbase = tj * BT + wc * 64;
#pragma unroll
    for (int m = 0; m < 4; ++m) {
#pragma unroll
        for (int n = 0; n < 4; ++n) {
            const int gi0 = rowbase + m * 16 + g * 4;
            const int gj  = colbase + n * 16 + fr;
            const float ncol = n2b[gj];
#pragma unroll
            for (int j = 0; j < 4; ++j) {
                const int gi = gi0 + j;
                const float cij = acc[m][n][j];
                float sq = fmaxf(n2b[gi] + ncol - 2.0f * cij, 0.0f);
                const float dist = sqrtf(sq);
                const float kd = __expf(-dist);
                const float s1 = S[(size_t)gi * NS + gj];
                if (diag) {
                    float d = (gi == gj) ? (1.0f - s1) : (kd - s1);
                    d *= (s1 > 0.0f) ? 1.0f : 0.0f;
                    local += d * d;
                } else {
                    const float s2 = St[(size_t)gi * NS + gj];  // = S[gj][gi]
                    const float d1 = (s1 > 0.0f) ? (kd - s1) : 0.0f;
                    const float d2 = (s2 > 0.0f) ? (kd - s2) : 0.0f;
                    local += d1 * d1 + d2 * d2;
                }
            }
        }
    }
#pragma unroll
    for (int off = 32; off >= 1; off >>= 1) local += __shfl_down(local, off, 64);
    if (lane == 0) red[wave] = local;
    __syncthreads();
    if (t == 0) partial[(size_t)b * NTILES_SYM + idx] = red[0] + red[1] + red[2] + red[3];
}

// =================== fallback path (R2, known-good; used if ws too small) ===================

__global__ __launch_bounds__(256) void norms_kernel(const float* __restrict__ dv,
                                                    float* __restrict__ n2) {
    const int row  = blockIdx.x * 4 + (threadIdx.x >> 6);
    const int lane = threadIdx.x & 63;
    const float4 v = *reinterpret_cast<const float4*>(dv + (size_t)row * DIM + lane * 4);
    float s = v.x * v.x + v.y * v.y + v.z * v.z + v.w * v.w;
#pragma unroll
    for (int off = 32; off >= 1; off >>= 1) s += __shfl_down(s, off, 64);
    if (lane == 0) n2[row] = s;
}

__global__ __launch_bounds__(256) void denom_kernel(const float* __restrict__ Smat,
                                                    float* __restrict__ dpartial) {
    const int t = threadIdx.x;
    const int lane = t & 63, wave = t >> 6;
    __shared__ float sred[4];
    float acc = 0.0f;
    const int base = blockIdx.x * 512;
#pragma unroll
    for (int r = 0; r < 2; ++r) {
        const int v4 = base + r * 256 + t;
        const float4 s4 = reinterpret_cast<const float4*>(Smat)[v4];
        const int idx0 = v4 * 4;
        const int i = idx0 >> 9;
#pragma unroll
        for (int c = 0; c < 4; ++c) {
            const float s = (&s4.x)[c];
            const int j = (idx0 + c) & (NS - 1);
            const float w = (s > 0.0f) ? 1.0f : 0.0f;
            const float e = (i == j) ? 1.0f : 0.0f;
            const float d = w - e;
            acc += d * d;
        }
    }
#pragma unroll
    for (int off = 32; off >= 1; off >>= 1) acc += __shfl_down(acc, off, 64);
    if (lane == 0) sred[wave] = acc;
    __syncthreads();
    if (t == 0) dpartial[blockIdx.x] = sred[0] + sred[1] + sred[2] + sred[3];
}

#define FLDSK 40
__global__ __launch_bounds__(256) void gram_f32_kernel(const float* __restrict__ dv,
                                                       const float* __restrict__ Smat,
                                                       const float* __restrict__ n2,
                                                       float* __restrict__ partial) {
    const int tile = blockIdx.x;
    const int b    = blockIdx.y;
    const int ti   = tile >> 2, tj = tile & 3;
    const int t    = threadIdx.x;
    const int wave = t >> 6, lane = t & 63;
    const int wr   = wave >> 1, wc = wave & 1;

    __shared__ bf16_t sA[BT * FLDSK];
    __shared__ bf16_t sB[BT * FLDSK];
    __shared__ float red[4];

    const float* Abase = dv + ((size_t)b * NS + (size_t)ti * BT) * DIM;
    const float* Bbase = dv + ((size_t)b * NS + (size_t)tj * BT) * DIM;

    f32x4 acc[4][4];
#pragma unroll
    for (int m = 0; m < 4; ++m)
#pragma unroll
        for (int n = 0; n < 4; ++n) acc[m][n] = (f32x4)(0.0f);

    const int fr = lane & 15;
    const int g  = lane >> 4;

    for (int ks = 0; ks < DIM; ks += 32) {
        float4 ra[4], rb[4];
#pragma unroll
        for (int i = 0; i < 4; ++i) {
            const int c   = i * 256 + t;
            const int row = c >> 3;
            const int kc  = (c & 7) * 4;
            ra[i] = *reinterpret_cast<const float4*>(Abase + (size_t)row * DIM + ks + kc);
            rb[i] = *reinterpret_cast<const float4*>(Bbase + (size_t)row * DIM + ks + kc);
        }
        __syncthreads();
#pragma unroll
        for (int i = 0; i < 4; ++i) {
            const int c   = i * 256 + t;
            const int row = c >> 3;
            const int kc  = (c & 7) * 4;
            bf16x4 va = { (bf16_t)ra[i].x, (bf16_t)ra[i].y, (bf16_t)ra[i].z, (bf16_t)ra[i].w };
            bf16x4 vb = { (bf16_t)rb[i].x, (bf16_t)rb[i].y, (bf16_t)rb[i].z, (bf16_t)rb[i].w };
            *reinterpret_cast<bf16x4*>(&sA[row * FLDSK + kc]) = va;
            *reinterpret_cast<bf16x4*>(&sB[row * FLDSK + kc]) = vb;
        }
        __syncthreads();

        bf16x8 afrag[4], bfrag[4];
#pragma unroll
        for (int m = 0; m < 4; ++m)
            afrag[m] = *reinterpret_cast<const bf16x8*>(&sA[(wr * 64 + m * 16 + fr) * FLDSK + g * 8]);
#pragma unroll
        for (int n = 0; n < 4; ++n)
            bfrag[n] = *reinterpret_cast<const bf16x8*>(&sB[(wc * 64 + n * 16 + fr) * FLDSK + g * 8]);
#pragma unroll
        for (int m = 0; m < 4; ++m)
#pragma unroll
            for (int n = 0; n < 4; ++n)
                acc[m][n] = __builtin_amdgcn_mfma_f32_16x16x32_bf16(afrag[m], bfrag[n], acc[m][n], 0, 0, 0);
    }

    float local = 0.0f;
    const float* n2b = n2 + (size_t)b * NS;
    const int rowbase = ti * BT + wr * 64;
    const int colbase = tj * BT + wc * 64;
#pragma unroll
    for (int m = 0; m < 4; ++m) {
#pragma unroll
        for (int n = 0; n < 4; ++n) {
            const int gi0 = rowbase + m * 16 + g * 4;
            const int gj  = colbase + n * 16 + fr;
            const float ncol = n2b[gj];
#pragma unroll
            for (int j = 0; j < 4; ++j) {
                const int gi = gi0 + j;
                const float cij = acc[m][n][j];
                float sq = fmaxf(n2b[gi] + ncol - 2.0f * cij, 0.0f);
                const float dist = sqrtf(sq);
                const float kd = __expf(-dist);
                const float s = Smat[(size_t)gi * NS + gj];
                const float w = (s > 0.0f) ? 1.0f : 0.0f;
                float d = (gi == gj) ? (1.0f - s) : (kd - s);
                d *= w;
                local += d * d;
            }
        }
    }
#pragma unroll
    for (int off = 32; off >= 1; off >>= 1) local += __shfl_down(local, off, 64);
    if (lane == 0) red[wave] = local;
    __syncthreads();
    if (t == 0) partial[(size_t)b * 16 + tile] = red[0] + red[1] + red[2] + red[3];
}

// =================== shared finalize ===================
__global__ __launch_bounds__(256) void finalize_kernel(const float* __restrict__ dpartial, int ndp,
                                                       const float* __restrict__ partial, int ntiles,
                                                       float* __restrict__ out) {
    const int t = threadIdx.x;
    const int lane = t & 63, wave = t >> 6;
    __shared__ float sred[4];
    __shared__ float sred2[4];

    float dacc = (t < ndp) ? dpartial[t] : 0.0f;
#pragma unroll
    for (int off = 32; off >= 1; off >>= 1) dacc += __shfl_down(dacc, off, 64);
    if (lane == 0) sred[wave] = dacc;
    __syncthreads();
    const float denom = sqrtf(sred[0] + sred[1] + sred[2] + sred[3]);

    float lsum = 0.0f;
    if (t < BATCH) {
        float ss = 0.0f;
        for (int k = 0; k < ntiles; ++k) ss += partial[(size_t)t * ntiles + k];
        lsum = 2.0f * sqrtf(ss) / denom;
    }
#pragma unroll
    for (int off = 32; off >= 1; off >>= 1) lsum += __shfl_down(lsum, off, 64);
    if (lane == 0) sred2[wave] = lsum;
    __syncthreads();
    if (t == 0) out[0] = sred2[0] + sred2[1] + sred2[2] + sred2[3];
}

extern "C" void kernel_launch(void* const* d_in, const int* in_sizes, int n_in,
                              void* d_out, int out_size, void* d_ws, size_t ws_size,
                              hipStream_t stream) {
    const float* dv   = (const float*)d_in[0];   // [128,512,256] fp32
    const float* Smat = (const float*)d_in[1];   // [512,512] fp32
    float* out = (float*)d_out;

    const size_t dvh_bytes = (size_t)BATCH * NS * DIM * 2;  // 33.55 MB
    const size_t st_bytes  = (size_t)NS * NS * 4;           // 1 MB
    const size_t n2_bytes  = (size_t)BATCH * NS * 4;        // 256 KB
    const size_t pt_bytes  = (size_t)BATCH * 16 * 4;
    const size_t dp_bytes  = 256 * 4;
    const size_t need = dvh_bytes + st_bytes + n2_bytes + pt_bytes + dp_bytes;

    if (ws_size >= need) {
        char* w = (char*)d_ws;
        bf16_t* dvh    = (bf16_t*)w;                 w += dvh_bytes;
        float* St      = (float*)w;                  w += st_bytes;
        float* n2      = (float*)w;                  w += n2_bytes;
        float* partial = (float*)w;                  w += pt_bytes;
        float* dpart   = (float*)w;

        conv_norms_kernel<<<dim3(BATCH * NS / 4), 256, 0, stream>>>(dv, dvh, n2);
        st_denom_kernel<<<dim3(256), 256, 0, stream>>>(Smat, St, dpart);
        gram_bf16_kernel<<<dim3(NTILES_SYM, BATCH), 256, 0, stream>>>(dvh, Smat, St, n2, partial);
        finalize_kernel<<<dim3(1), 256, 0, stream>>>(dpart, 256, partial, NTILES_SYM, out);
    } else {
        float* n2      = (float*)d_ws;
        float* partial = n2 + (size_t)BATCH * NS;
        float* dpart   = partial + (size_t)BATCH * 16;

        norms_kernel<<<dim3(BATCH * NS / 4), 256, 0, stream>>>(dv, n2);
        denom_kernel<<<dim3(128), 256, 0, stream>>>(Smat, dpart);
        gram_f32_kernel<<<dim3(16, BATCH), 256, 0, stream>>>(dv, Smat, n2, partial);
        finalize_kernel<<<dim3(1), 256, 0, stream>>>(dpart, 128, partial, 16, out);
    }
}

// Round 4
// 71.539 us; speedup vs baseline: 1.4247x; 1.4247x over previous
//
#include <hip/hip_runtime.h>
#include <hip/hip_bf16.h>

typedef __bf16 bf16_t;
typedef __bf16 bf16x4 __attribute__((ext_vector_type(4)));
typedef __bf16 bf16x8 __attribute__((ext_vector_type(8)));
typedef float f32x4 __attribute__((ext_vector_type(4)));

#define BATCH 128
#define NS 512
#define DIM 256
#define BT 128    // output tile (M = N = 128)
#define NTILES_SYM 10
#define BK 64
#define LDSK 72   // padded k-stride (144 B rows)

// =================== fast path (bf16 pre-converted) ===================

// Kernel A: fused convert fp32->bf16 + row norms. One wave per row (256 f32).
__global__ __launch_bounds__(256) void conv_norms_kernel(const float* __restrict__ dv,
                                                         bf16_t* __restrict__ dvh,
                                                         float* __restrict__ n2) {
    const int row  = blockIdx.x * 4 + (threadIdx.x >> 6);
    const int lane = threadIdx.x & 63;
    const float4 v = *reinterpret_cast<const float4*>(dv + (size_t)row * DIM + lane * 4);
    bf16x4 hv = { (bf16_t)v.x, (bf16_t)v.y, (bf16_t)v.z, (bf16_t)v.w };
    *reinterpret_cast<bf16x4*>(dvh + (size_t)row * DIM + lane * 4) = hv;
    float s = v.x * v.x + v.y * v.y + v.z * v.z + v.w * v.w;
#pragma unroll
    for (int off = 32; off >= 1; off >>= 1) s += __shfl_down(s, off, 64);
    if (lane == 0) n2[row] = s;
}

// Kernel B: St = S^T (LDS 32x33 tiles) fused with denom partials ||W-I||_F^2.
__global__ __launch_bounds__(256) void st_denom_kernel(const float* __restrict__ S,
                                                       float* __restrict__ St,
                                                       float* __restrict__ dpartial) {
    const int bi = blockIdx.x >> 4, bj = blockIdx.x & 15;
    const int t  = threadIdx.x;
    const int c  = t & 31, r0 = t >> 5;
    __shared__ float tileS[32][33];
    __shared__ float red[4];
    float dacc = 0.0f;
#pragma unroll
    for (int k = 0; k < 4; ++k) {
        const int r  = r0 + k * 8;
        const int gi = bi * 32 + r, gj = bj * 32 + c;
        const float s = S[(size_t)gi * NS + gj];
        tileS[r][c] = s;
        const float w = (s > 0.0f) ? 1.0f : 0.0f;
        const float e = (gi == gj) ? 1.0f : 0.0f;
        const float d = w - e;
        dacc += d * d;
    }
    __syncthreads();
#pragma unroll
    for (int k = 0; k < 4; ++k) {
        const int r = r0 + k * 8;
        St[(size_t)(bj * 32 + r) * NS + bi * 32 + c] = tileS[c][r];
    }
    const int lane = t & 63, wave = t >> 6;
#pragma unroll
    for (int off = 32; off >= 1; off >>= 1) dacc += __shfl_down(dacc, off, 64);
    if (lane == 0) red[wave] = dacc;
    __syncthreads();
    if (t == 0) dpartial[blockIdx.x] = red[0] + red[1] + red[2] + red[3];
}

// Kernel C: symmetric batched Gram + fused epilogue, reg-prefetch pipelined.
// grid 1280 blocks x 512 threads = 8 waves (2x4), each wave owns 64x32.
__global__ __launch_bounds__(512) void gram_bf16_kernel(const bf16_t* __restrict__ dvh,
                                                        const float* __restrict__ S,
                                                        const float* __restrict__ St,
                                                        const float* __restrict__ n2,
                                                        float* __restrict__ partial) {
    // XCD-aware swizzle: XCD x owns batches [x*16, (x+1)*16) -> ~4MB L2 working set
    const int bid  = blockIdx.x;
    const int work = (bid & 7) * 160 + (bid >> 3);
    const int b    = work / 10;
    const int idx  = work - b * 10;   // 0..9 upper-triangular tile enumeration
    int ti, tj;
    if (idx < 4)      { ti = 0; tj = idx; }
    else if (idx < 7) { ti = 1; tj = idx - 3; }
    else if (idx < 9) { ti = 2; tj = idx - 5; }
    else              { ti = 3; tj = 3; }
    const bool diag = (ti == tj);
    const int t    = threadIdx.x;
    const int wave = t >> 6, lane = t & 63;
    const int wr   = wave >> 2, wc = wave & 3;

    __shared__ bf16_t sA[BT * LDSK];
    __shared__ bf16_t sB[BT * LDSK];
    __shared__ float red[8];

    const bf16_t* Abase = dvh + ((size_t)b * NS + (size_t)ti * BT) * DIM;
    const bf16_t* Bbase = dvh + ((size_t)b * NS + (size_t)tj * BT) * DIM;

    const int srow = t >> 3;        // 0..63 (staging row within half-panel)
    const int skc  = (t & 7) * 8;   // staging k offset

    f32x4 acc[4][2];
#pragma unroll
    for (int m = 0; m < 4; ++m)
#pragma unroll
        for (int n = 0; n < 2; ++n) acc[m][n] = (f32x4)(0.0f);

    const int fr = lane & 15;   // fragment row within 16
    const int g  = lane >> 4;   // k-group (8 consecutive k)

    bf16x8 pa0[2], pb0[2], pa1[2], pb1[2];

#define LOADSTEP(ra, rb, ks)                                                            \
    do {                                                                                \
        _Pragma("unroll") for (int i = 0; i < 2; ++i) {                                 \
            const int row = i * 64 + srow;                                              \
            ra[i] = *reinterpret_cast<const bf16x8*>(Abase + (size_t)row * DIM + (ks) + skc); \
            if (!diag)                                                                  \
                rb[i] = *reinterpret_cast<const bf16x8*>(Bbase + (size_t)row * DIM + (ks) + skc); \
        }                                                                               \
    } while (0)

#define STORESTEP(ra, rb)                                                               \
    do {                                                                                \
        _Pragma("unroll") for (int i = 0; i < 2; ++i) {                                 \
            const int row = i * 64 + srow;                                              \
            *reinterpret_cast<bf16x8*>(&sA[row * LDSK + skc]) = ra[i];                  \
            if (!diag) *reinterpret_cast<bf16x8*>(&sB[row * LDSK + skc]) = rb[i];       \
        }                                                                               \
    } while (0)

    LOADSTEP(pa0, pb0, 0);

#pragma unroll
    for (int step = 0; step < 4; ++step) {
        __syncthreads();   // previous compute done reading LDS
        if (step & 1) STORESTEP(pa1, pb1);
        else          STORESTEP(pa0, pb0);
        __syncthreads();   // writes visible
        // issue next step's global loads now -> in flight during MFMA phase (T14)
        if (step < 3) {
            if (step & 1) LOADSTEP(pa0, pb0, (step + 1) * BK);
            else          LOADSTEP(pa1, pb1, (step + 1) * BK);
        }
        const bf16_t* sBp = diag ? sA : sB;
#pragma unroll
        for (int h = 0; h < 2; ++h) {
            bf16x8 af[4], bfg[2];
#pragma unroll
            for (int m = 0; m < 4; ++m)
                af[m] = *reinterpret_cast<const bf16x8*>(&sA[(wr * 64 + m * 16 + fr) * LDSK + h * 32 + g * 8]);
#pragma unroll
            for (int n = 0; n < 2; ++n)
                bfg[n] = *reinterpret_cast<const bf16x8*>(&sBp[(wc * 32 + n * 16 + fr) * LDSK + h * 32 + g * 8]);
#pragma unroll
            for (int m = 0; m < 4; ++m)
#pragma unroll
                for (int n = 0; n < 2; ++n)
                    acc[m][n] = __builtin_amdgcn_mfma_f32_16x16x32_bf16(af[m], bfg[n], acc[m][n], 0, 0, 0);
        }
    }
#undef LOADSTEP
#undef STORESTEP

    // epilogue: C/D layout col = lane&15, row = (lane>>4)*4 + j [guide-verified]
    float local = 0.0f;
    const float* n2b = n2 + (size_t)b * NS;
    const int rowbase = ti * BT + wr * 64;
    const int colbase = tj * BT + wc * 32;
#pragma unroll
    for (int m = 0; m < 4; ++m) {
#pragma unroll
        for (int n = 0; n < 2; ++n) {
            const int gi0 = rowbase + m * 16 + g * 4;
            const int gj  = colbase + n * 16 + fr;
            const float ncol = n2b[gj];
#pragma unroll
            for (int j = 0; j < 4; ++j) {
                const int gi = gi0 + j;
                const float cij = acc[m][n][j];
                float sq = fmaxf(n2b[gi] + ncol - 2.0f * cij, 0.0f);
                const float dist = sqrtf(sq);
                const float kd = __expf(-dist);
                const float s1 = S[(size_t)gi * NS + gj];
                if (diag) {
                    float d = (gi == gj) ? (1.0f - s1) : (kd - s1);
                    d *= (s1 > 0.0f) ? 1.0f : 0.0f;
                    local += d * d;
                } else {
                    const float s2 = St[(size_t)gi * NS + gj];  // = S[gj][gi]
                    const float d1 = (s1 > 0.0f) ? (kd - s1) : 0.0f;
                    const float d2 = (s2 > 0.0f) ? (kd - s2) : 0.0f;
                    local += d1 * d1 + d2 * d2;
                }
            }
        }
    }
#pragma unroll
    for (int off = 32; off >= 1; off >>= 1) local += __shfl_down(local, off, 64);
    if (lane == 0) red[wave] = local;
    __syncthreads();
    if (t == 0) {
        float s = 0.0f;
#pragma unroll
        for (int w = 0; w < 8; ++w) s += red[w];
        partial[(size_t)b * NTILES_SYM + idx] = s;
    }
}

// =================== fallback path (R2, known-good; used if ws too small) ===================

__global__ __launch_bounds__(256) void norms_kernel(const float* __restrict__ dv,
                                                    float* __restrict__ n2) {
    const int row  = blockIdx.x * 4 + (threadIdx.x >> 6);
    const int lane = threadIdx.x & 63;
    const float4 v = *reinterpret_cast<const float4*>(dv + (size_t)row * DIM + lane * 4);
    float s = v.x * v.x + v.y * v.y + v.z * v.z + v.w * v.w;
#pragma unroll
    for (int off = 32; off >= 1; off >>= 1) s += __shfl_down(s, off, 64);
    if (lane == 0) n2[row] = s;
}

__global__ __launch_bounds__(256) void denom_kernel(const float* __restrict__ Smat,
                                                    float* __restrict__ dpartial) {
    const int t = threadIdx.x;
    const int lane = t & 63, wave = t >> 6;
    __shared__ float sred[4];
    float acc = 0.0f;
    const int base = blockIdx.x * 512;
#pragma unroll
    for (int r = 0; r < 2; ++r) {
        const int v4 = base + r * 256 + t;
        const float4 s4 = reinterpret_cast<const float4*>(Smat)[v4];
        const int idx0 = v4 * 4;
        const int i = idx0 >> 9;
#pragma unroll
        for (int c = 0; c < 4; ++c) {
            const float s = (&s4.x)[c];
            const int j = (idx0 + c) & (NS - 1);
            const float w = (s > 0.0f) ? 1.0f : 0.0f;
            const float e = (i == j) ? 1.0f : 0.0f;
            const float d = w - e;
            acc += d * d;
        }
    }
#pragma unroll
    for (int off = 32; off >= 1; off >>= 1) acc += __shfl_down(acc, off, 64);
    if (lane == 0) sred[wave] = acc;
    __syncthreads();
    if (t == 0) dpartial[blockIdx.x] = sred[0] + sred[1] + sred[2] + sred[3];
}

#define FLDSK 40
__global__ __launch_bounds__(256) void gram_f32_kernel(const float* __restrict__ dv,
                                                       const float* __restrict__ Smat,
                                                       const float* __restrict__ n2,
                                                       float* __restrict__ partial) {
    const int tile = blockIdx.x;
    const int b    = blockIdx.y;
    const int ti   = tile >> 2, tj = tile & 3;
    const int t    = threadIdx.x;
    const int wave = t >> 6, lane = t & 63;
    const int wr   = wave >> 1, wc = wave & 1;

    __shared__ bf16_t sA[BT * FLDSK];
    __shared__ bf16_t sB[BT * FLDSK];
    __shared__ float red[4];

    const float* Abase = dv + ((size_t)b * NS + (size_t)ti * BT) * DIM;
    const float* Bbase = dv + ((size_t)b * NS + (size_t)tj * BT) * DIM;

    f32x4 acc[4][4];
#pragma unroll
    for (int m = 0; m < 4; ++m)
#pragma unroll
        for (int n = 0; n < 4; ++n) acc[m][n] = (f32x4)(0.0f);

    const int fr = lane & 15;
    const int g  = lane >> 4;

    for (int ks = 0; ks < DIM; ks += 32) {
        float4 ra[4], rb[4];
#pragma unroll
        for (int i = 0; i < 4; ++i) {
            const int c   = i * 256 + t;
            const int row = c >> 3;
            const int kc  = (c & 7) * 4;
            ra[i] = *reinterpret_cast<const float4*>(Abase + (size_t)row * DIM + ks + kc);
            rb[i] = *reinterpret_cast<const float4*>(Bbase + (size_t)row * DIM + ks + kc);
        }
        __syncthreads();
#pragma unroll
        for (int i = 0; i < 4; ++i) {
            const int c   = i * 256 + t;
            const int row = c >> 3;
            const int kc  = (c & 7) * 4;
            bf16x4 va = { (bf16_t)ra[i].x, (bf16_t)ra[i].y, (bf16_t)ra[i].z, (bf16_t)ra[i].w };
            bf16x4 vb = { (bf16_t)rb[i].x, (bf16_t)rb[i].y, (bf16_t)rb[i].z, (bf16_t)rb[i].w };
            *reinterpret_cast<bf16x4*>(&sA[row * FLDSK + kc]) = va;
            *reinterpret_cast<bf16x4*>(&sB[row * FLDSK + kc]) = vb;
        }
        __syncthreads();

        bf16x8 afrag[4], bfrag[4];
#pragma unroll
        for (int m = 0; m < 4; ++m)
            afrag[m] = *reinterpret_cast<const bf16x8*>(&sA[(wr * 64 + m * 16 + fr) * FLDSK + g * 8]);
#pragma unroll
        for (int n = 0; n < 4; ++n)
            bfrag[n] = *reinterpret_cast<const bf16x8*>(&sB[(wc * 64 + n * 16 + fr) * FLDSK + g * 8]);
#pragma unroll
        for (int m = 0; m < 4; ++m)
#pragma unroll
            for (int n = 0; n < 4; ++n)
                acc[m][n] = __builtin_amdgcn_mfma_f32_16x16x32_bf16(afrag[m], bfrag[n], acc[m][n], 0, 0, 0);
    }

    float local = 0.0f;
    const float* n2b = n2 + (size_t)b * NS;
    const int rowbase = ti * BT + wr * 64;
    const int colbase = tj * BT + wc * 64;
#pragma unroll
    for (int m = 0; m < 4; ++m) {
#pragma unroll
        for (int n = 0; n < 4; ++n) {
            const int gi0 = rowbase + m * 16 + g * 4;
            const int gj  = colbase + n * 16 + fr;
            const float ncol = n2b[gj];
#pragma unroll
            for (int j = 0; j < 4; ++j) {
                const int gi = gi0 + j;
                const float cij = acc[m][n][j];
                float sq = fmaxf(n2b[gi] + ncol - 2.0f * cij, 0.0f);
                const float dist = sqrtf(sq);
                const float kd = __expf(-dist);
                const float s = Smat[(size_t)gi * NS + gj];
                const float w = (s > 0.0f) ? 1.0f : 0.0f;
                float d = (gi == gj) ? (1.0f - s) : (kd - s);
                d *= w;
                local += d * d;
            }
        }
    }
#pragma unroll
    for (int off = 32; off >= 1; off >>= 1) local += __shfl_down(local, off, 64);
    if (lane == 0) red[wave] = local;
    __syncthreads();
    if (t == 0) partial[(size_t)b * 16 + tile] = red[0] + red[1] + red[2] + red[3];
}

// =================== shared finalize ===================
__global__ __launch_bounds__(256) void finalize_kernel(const float* __restrict__ dpartial, int ndp,
                                                       const float* __restrict__ partial, int ntiles,
                                                       float* __restrict__ out) {
    const int t = threadIdx.x;
    const int lane = t & 63, wave = t >> 6;
    __shared__ float sred[4];
    __shared__ float sred2[4];

    float dacc = (t < ndp) ? dpartial[t] : 0.0f;
#pragma unroll
    for (int off = 32; off >= 1; off >>= 1) dacc += __shfl_down(dacc, off, 64);
    if (lane == 0) sred[wave] = dacc;
    __syncthreads();
    const float denom = sqrtf(sred[0] + sred[1] + sred[2] + sred[3]);

    float lsum = 0.0f;
    if (t < BATCH) {
        float ss = 0.0f;
        for (int k = 0; k < ntiles; ++k) ss += partial[(size_t)t * ntiles + k];
        lsum = 2.0f * sqrtf(ss) / denom;
    }
#pragma unroll
    for (int off = 32; off >= 1; off >>= 1) lsum += __shfl_down(lsum, off, 64);
    if (lane == 0) sred2[wave] = lsum;
    __syncthreads();
    if (t == 0) out[0] = sred2[0] + sred2[1] + sred2[2] + sred2[3];
}

extern "C" void kernel_launch(void* const* d_in, const int* in_sizes, int n_in,
                              void* d_out, int out_size, void* d_ws, size_t ws_size,
                              hipStream_t stream) {
    const float* dv   = (const float*)d_in[0];   // [128,512,256] fp32
    const float* Smat = (const float*)d_in[1];   // [512,512] fp32
    float* out = (float*)d_out;

    const size_t dvh_bytes = (size_t)BATCH * NS * DIM * 2;  // 33.55 MB
    const size_t st_bytes  = (size_t)NS * NS * 4;           // 1 MB
    const size_t n2_bytes  = (size_t)BATCH * NS * 4;        // 256 KB
    const size_t pt_bytes  = (size_t)BATCH * 16 * 4;
    const size_t dp_bytes  = 256 * 4;
    const size_t need = dvh_bytes + st_bytes + n2_bytes + pt_bytes + dp_bytes;

    if (ws_size >= need) {
        char* w = (char*)d_ws;
        bf16_t* dvh    = (bf16_t*)w;                 w += dvh_bytes;
        float* St      = (float*)w;                  w += st_bytes;
        float* n2      = (float*)w;                  w += n2_bytes;
        float* partial = (float*)w;                  w += pt_bytes;
        float* dpart   = (float*)w;

        conv_norms_kernel<<<dim3(BATCH * NS / 4), 256, 0, stream>>>(dv, dvh, n2);
        st_denom_kernel<<<dim3(256), 256, 0, stream>>>(Smat, St, dpart);
        gram_bf16_kernel<<<dim3(NTILES_SYM * BATCH), 512, 0, stream>>>(dvh, Smat, St, n2, partial);
        finalize_kernel<<<dim3(1), 256, 0, stream>>>(dpart, 256, partial, NTILES_SYM, out);
    } else {
        float* n2      = (float*)d_ws;
        float* partial = n2 + (size_t)BATCH * NS;
        float* dpart   = partial + (size_t)BATCH * 16;

        norms_kernel<<<dim3(BATCH * NS / 4), 256, 0, stream>>>(dv, n2);
        denom_kernel<<<dim3(128), 256, 0, stream>>>(Smat, dpart);
        gram_f32_kernel<<<dim3(16, BATCH), 256, 0, stream>>>(dv, Smat, n2, partial);
        finalize_kernel<<<dim3(1), 256, 0, stream>>>(dpart, 128, partial, 16, out);
    }
}

// Round 5
// 67.015 us; speedup vs baseline: 1.5209x; 1.0675x over previous
//
#include <hip/hip_runtime.h>
#include <hip/hip_bf16.h>

typedef __bf16 bf16_t;
typedef __bf16 bf16x4 __attribute__((ext_vector_type(4)));
typedef __bf16 bf16x8 __attribute__((ext_vector_type(8)));
typedef float f32x4 __attribute__((ext_vector_type(4)));
typedef float f32x16 __attribute__((ext_vector_type(16)));

#define BATCH 128
#define NS 512
#define DIM 256
#define BT 128    // output tile (M = N = 128)
#define NT 10     // upper-triangular 4x4 tile count
#define LDSK 264  // padded k-stride (528 B rows): even bank spread for b128 reads

// =================== Kernel B: St = S^T fused with denom partials ===================
__global__ __launch_bounds__(256) void st_denom_kernel(const float* __restrict__ S,
                                                       float* __restrict__ St,
                                                       float* __restrict__ dpartial) {
    const int bi = blockIdx.x >> 4, bj = blockIdx.x & 15;
    const int t  = threadIdx.x;
    const int c  = t & 31, r0 = t >> 5;
    __shared__ float tileS[32][33];
    __shared__ float red[4];
    float dacc = 0.0f;
#pragma unroll
    for (int k = 0; k < 4; ++k) {
        const int r  = r0 + k * 8;
        const int gi = bi * 32 + r, gj = bj * 32 + c;
        const float s = S[(size_t)gi * NS + gj];
        tileS[r][c] = s;
        const float w = (s > 0.0f) ? 1.0f : 0.0f;
        const float e = (gi == gj) ? 1.0f : 0.0f;
        const float d = w - e;
        dacc += d * d;
    }
    __syncthreads();
#pragma unroll
    for (int k = 0; k < 4; ++k) {
        const int r = r0 + k * 8;
        St[(size_t)(bj * 32 + r) * NS + bi * 32 + c] = tileS[c][r];
    }
    const int lane = t & 63, wave = t >> 6;
#pragma unroll
    for (int off = 32; off >= 1; off >>= 1) dacc += __shfl_down(dacc, off, 64);
    if (lane == 0) red[wave] = dacc;
    __syncthreads();
    if (t == 0) dpartial[blockIdx.x] = red[0] + red[1] + red[2] + red[3];
}

// =================== Kernel C: fully fused gram (stage-once, one barrier) ===================
// grid 1280 x 512 threads (8 waves, 2x4); wave owns 64x32 = 2 x mfma_32x32.
// Stages fp32 -> bf16 LDS panels + computes row norms in the same pass.
__global__ __launch_bounds__(512) void gram_fused_kernel(const float* __restrict__ dv,
                                                         const float* __restrict__ S,
                                                         const float* __restrict__ St,
                                                         float* __restrict__ partial) {
    const int bid  = blockIdx.x;
    const int work = (bid & 7) * 160 + (bid >> 3);   // bijective XCD swizzle (1280 = 8*160)
    const int b    = work / NT;
    const int idx  = work - b * NT;
    int ti, tj;
    if (idx < 4)      { ti = 0; tj = idx; }
    else if (idx < 7) { ti = 1; tj = idx - 3; }
    else if (idx < 9) { ti = 2; tj = idx - 5; }
    else              { ti = 3; tj = 3; }
    const bool diag = (ti == tj);
    const int t    = threadIdx.x;
    const int wave = t >> 6, lane = t & 63;
    const int wr   = wave >> 2, wc = wave & 3;
    const int col  = lane & 31, kh = lane >> 5;

    __shared__ bf16_t sA[BT * LDSK];
    __shared__ bf16_t sB[BT * LDSK];
    __shared__ float n2A[BT];
    __shared__ float n2B[BT];
    __shared__ float red[8];

    // ---- staging: fp32 global read -> n2 fma -> bf16 convert -> LDS b128 write ----
    {
        const int r = t >> 2, q = t & 3;   // 4 threads per row, 64 k each
        const float* Arow = dv + ((size_t)b * NS + (size_t)ti * BT + r) * DIM;
        const float* Brow = dv + ((size_t)b * NS + (size_t)tj * BT + r) * DIM;
        float na = 0.0f, nb = 0.0f;
#pragma unroll
        for (int j = 0; j < 8; ++j) {
            const int k0 = j * 32 + q * 8;
            const f32x4 a0 = *reinterpret_cast<const f32x4*>(Arow + k0);
            const f32x4 a1 = *reinterpret_cast<const f32x4*>(Arow + k0 + 4);
            na += a0[0]*a0[0] + a0[1]*a0[1] + a0[2]*a0[2] + a0[3]*a0[3]
                + a1[0]*a1[0] + a1[1]*a1[1] + a1[2]*a1[2] + a1[3]*a1[3];
            bf16x8 ha = { (bf16_t)a0[0], (bf16_t)a0[1], (bf16_t)a0[2], (bf16_t)a0[3],
                          (bf16_t)a1[0], (bf16_t)a1[1], (bf16_t)a1[2], (bf16_t)a1[3] };
            *reinterpret_cast<bf16x8*>(&sA[r * LDSK + k0]) = ha;
            if (!diag) {
                const f32x4 b0 = *reinterpret_cast<const f32x4*>(Brow + k0);
                const f32x4 b1 = *reinterpret_cast<const f32x4*>(Brow + k0 + 4);
                nb += b0[0]*b0[0] + b0[1]*b0[1] + b0[2]*b0[2] + b0[3]*b0[3]
                    + b1[0]*b1[0] + b1[1]*b1[1] + b1[2]*b1[2] + b1[3]*b1[3];
                bf16x8 hb = { (bf16_t)b0[0], (bf16_t)b0[1], (bf16_t)b0[2], (bf16_t)b0[3],
                              (bf16_t)b1[0], (bf16_t)b1[1], (bf16_t)b1[2], (bf16_t)b1[3] };
                *reinterpret_cast<bf16x8*>(&sB[r * LDSK + k0]) = hb;
            }
        }
        // reduce n2 over the 4 k-quarters (lane bits 0-1)
        na += __shfl_xor(na, 1, 64);
        na += __shfl_xor(na, 2, 64);
        if (!diag) {
            nb += __shfl_xor(nb, 1, 64);
            nb += __shfl_xor(nb, 2, 64);
        }
        if (q == 0) { n2A[r] = na; n2B[r] = diag ? na : nb; }
    }
    __syncthreads();

    // ---- K-loop: register-only, 16 x (3 ds_read_b128 + 2 mfma_32x32x16) ----
    f32x16 acc0 = (f32x16)(0.0f);
    f32x16 acc1 = (f32x16)(0.0f);
    {
        const bf16_t* sBp = diag ? sA : sB;
        const int arow0 = (wr * 64 + col) * LDSK;
        const int arow1 = (wr * 64 + 32 + col) * LDSK;
        const int brow  = (wc * 32 + col) * LDSK;
        const int kb    = kh * 8;
        __builtin_amdgcn_s_setprio(1);
#pragma unroll
        for (int s = 0; s < 16; ++s) {
            const int ko = s * 16 + kb;
            const bf16x8 a0 = *reinterpret_cast<const bf16x8*>(&sA[arow0 + ko]);
            const bf16x8 a1 = *reinterpret_cast<const bf16x8*>(&sA[arow1 + ko]);
            const bf16x8 bb = *reinterpret_cast<const bf16x8*>(&sBp[brow + ko]);
            acc0 = __builtin_amdgcn_mfma_f32_32x32x16_bf16(a0, bb, acc0, 0, 0, 0);
            acc1 = __builtin_amdgcn_mfma_f32_32x32x16_bf16(a1, bb, acc1, 0, 0, 0);
        }
        __builtin_amdgcn_s_setprio(0);
    }

    // ---- epilogue: C/D 32x32 layout col=lane&31, row=(reg&3)+8*(reg>>2)+4*(lane>>5) ----
    float local = 0.0f;
    {
        const int lj = wc * 32 + col;
        const int gj = tj * BT + lj;
        const float n2j = n2B[lj];
        const float* Srow  = S  + (size_t)gj * NS + (size_t)ti * BT;  // S[gj][gi...]
        const float* Strow = St + (size_t)gj * NS + (size_t)ti * BT;  // St[gj][gi] = S[gi][gj]
#pragma unroll
        for (int m = 0; m < 2; ++m) {
            const f32x16 av = m ? acc1 : acc0;
#pragma unroll
            for (int h = 0; h < 4; ++h) {
                const int li0 = wr * 64 + m * 32 + h * 8 + kh * 4;
                const f32x4 s1q = *reinterpret_cast<const f32x4*>(Strow + li0);
                f32x4 s2q = (f32x4)(0.0f);
                if (!diag) s2q = *reinterpret_cast<const f32x4*>(Srow + li0);
#pragma unroll
                for (int e = 0; e < 4; ++e) {
                    const int li = li0 + e;
                    const float c = av[h * 4 + e];
                    const float sq = fmaxf(n2A[li] + n2j - 2.0f * c, 0.0f);
                    const float dist = sqrtf(sq);
                    const float kd = __expf(-dist);
                    const float s1 = s1q[e];
                    if (diag) {
                        float d = (li == lj) ? (1.0f - s1) : (kd - s1);
                        d *= (s1 > 0.0f) ? 1.0f : 0.0f;
                        local += d * d;
                    } else {
                        const float s2 = s2q[e];
                        const float d1 = (s1 > 0.0f) ? (kd - s1) : 0.0f;
                        const float d2 = (s2 > 0.0f) ? (kd - s2) : 0.0f;
                        local += d1 * d1 + d2 * d2;
                    }
                }
            }
        }
    }
#pragma unroll
    for (int off = 32; off >= 1; off >>= 1) local += __shfl_down(local, off, 64);
    if (lane == 0) red[wave] = local;
    __syncthreads();
    if (t == 0) {
        float s = 0.0f;
#pragma unroll
        for (int w = 0; w < 8; ++w) s += red[w];
        partial[(size_t)b * NT + idx] = s;
    }
}

// =================== fallback path (R2, known-good; used if ws too small) ===================

__global__ __launch_bounds__(256) void norms_kernel(const float* __restrict__ dv,
                                                    float* __restrict__ n2) {
    const int row  = blockIdx.x * 4 + (threadIdx.x >> 6);
    const int lane = threadIdx.x & 63;
    const float4 v = *reinterpret_cast<const float4*>(dv + (size_t)row * DIM + lane * 4);
    float s = v.x * v.x + v.y * v.y + v.z * v.z + v.w * v.w;
#pragma unroll
    for (int off = 32; off >= 1; off >>= 1) s += __shfl_down(s, off, 64);
    if (lane == 0) n2[row] = s;
}

__global__ __launch_bounds__(256) void denom_kernel(const float* __restrict__ Smat,
                                                    float* __restrict__ dpartial) {
    const int t = threadIdx.x;
    const int lane = t & 63, wave = t >> 6;
    __shared__ float sred[4];
    float acc = 0.0f;
    const int base = blockIdx.x * 512;
#pragma unroll
    for (int r = 0; r < 2; ++r) {
        const int v4 = base + r * 256 + t;
        const float4 s4 = reinterpret_cast<const float4*>(Smat)[v4];
        const int idx0 = v4 * 4;
        const int i = idx0 >> 9;
#pragma unroll
        for (int c = 0; c < 4; ++c) {
            const float s = (&s4.x)[c];
            const int j = (idx0 + c) & (NS - 1);
            const float w = (s > 0.0f) ? 1.0f : 0.0f;
            const float e = (i == j) ? 1.0f : 0.0f;
            const float d = w - e;
            acc += d * d;
        }
    }
#pragma unroll
    for (int off = 32; off >= 1; off >>= 1) acc += __shfl_down(acc, off, 64);
    if (lane == 0) sred[wave] = acc;
    __syncthreads();
    if (t == 0) dpartial[blockIdx.x] = sred[0] + sred[1] + sred[2] + sred[3];
}

#define FLDSK 40
__global__ __launch_bounds__(256) void gram_f32_kernel(const float* __restrict__ dv,
                                                       const float* __restrict__ Smat,
                                                       const float* __restrict__ n2,
                                                       float* __restrict__ partial) {
    const int tile = blockIdx.x;
    const int b    = blockIdx.y;
    const int ti   = tile >> 2, tj = tile & 3;
    const int t    = threadIdx.x;
    const int wave = t >> 6, lane = t & 63;
    const int wr   = wave >> 1, wc = wave & 1;

    __shared__ bf16_t sA[BT * FLDSK];
    __shared__ bf16_t sB[BT * FLDSK];
    __shared__ float red[4];

    const float* Abase = dv + ((size_t)b * NS + (size_t)ti * BT) * DIM;
    const float* Bbase = dv + ((size_t)b * NS + (size_t)tj * BT) * DIM;

    f32x4 acc[4][4];
#pragma unroll
    for (int m = 0; m < 4; ++m)
#pragma unroll
        for (int n = 0; n < 4; ++n) acc[m][n] = (f32x4)(0.0f);

    const int fr = lane & 15;
    const int g  = lane >> 4;

    for (int ks = 0; ks < DIM; ks += 32) {
        float4 ra[4], rb[4];
#pragma unroll
        for (int i = 0; i < 4; ++i) {
            const int c   = i * 256 + t;
            const int row = c >> 3;
            const int kc  = (c & 7) * 4;
            ra[i] = *reinterpret_cast<const float4*>(Abase + (size_t)row * DIM + ks + kc);
            rb[i] = *reinterpret_cast<const float4*>(Bbase + (size_t)row * DIM + ks + kc);
        }
        __syncthreads();
#pragma unroll
        for (int i = 0; i < 4; ++i) {
            const int c   = i * 256 + t;
            const int row = c >> 3;
            const int kc  = (c & 7) * 4;
            bf16x4 va = { (bf16_t)ra[i].x, (bf16_t)ra[i].y, (bf16_t)ra[i].z, (bf16_t)ra[i].w };
            bf16x4 vb = { (bf16_t)rb[i].x, (bf16_t)rb[i].y, (bf16_t)rb[i].z, (bf16_t)rb[i].w };
            *reinterpret_cast<bf16x4*>(&sA[row * FLDSK + kc]) = va;
            *reinterpret_cast<bf16x4*>(&sB[row * FLDSK + kc]) = vb;
        }
        __syncthreads();

        bf16x8 afrag[4], bfrag[4];
#pragma unroll
        for (int m = 0; m < 4; ++m)
            afrag[m] = *reinterpret_cast<const bf16x8*>(&sA[(wr * 64 + m * 16 + fr) * FLDSK + g * 8]);
#pragma unroll
        for (int n = 0; n < 4; ++n)
            bfrag[n] = *reinterpret_cast<const bf16x8*>(&sB[(wc * 64 + n * 16 + fr) * FLDSK + g * 8]);
#pragma unroll
        for (int m = 0; m < 4; ++m)
#pragma unroll
            for (int n = 0; n < 4; ++n)
                acc[m][n] = __builtin_amdgcn_mfma_f32_16x16x32_bf16(afrag[m], bfrag[n], acc[m][n], 0, 0, 0);
    }

    float local = 0.0f;
    const float* n2b = n2 + (size_t)b * NS;
    const int rowbase = ti * BT + wr * 64;
    const int colbase = tj * BT + wc * 64;
#pragma unroll
    for (int m = 0; m < 4; ++m) {
#pragma unroll
        for (int n = 0; n < 4; ++n) {
            const int gi0 = rowbase + m * 16 + g * 4;
            const int gj  = colbase + n * 16 + fr;
            const float ncol = n2b[gj];
#pragma unroll
            for (int j = 0; j < 4; ++j) {
                const int gi = gi0 + j;
                const float cij = acc[m][n][j];
                float sq = fmaxf(n2b[gi] + ncol - 2.0f * cij, 0.0f);
                const float dist = sqrtf(sq);
                const float kd = __expf(-dist);
                const float s = Smat[(size_t)gi * NS + gj];
                const float w = (s > 0.0f) ? 1.0f : 0.0f;
                float d = (gi == gj) ? (1.0f - s) : (kd - s);
                d *= w;
                local += d * d;
            }
        }
    }
#pragma unroll
    for (int off = 32; off >= 1; off >>= 1) local += __shfl_down(local, off, 64);
    if (lane == 0) red[wave] = local;
    __syncthreads();
    if (t == 0) partial[(size_t)b * 16 + tile] = red[0] + red[1] + red[2] + red[3];
}

// =================== shared finalize ===================
__global__ __launch_bounds__(256) void finalize_kernel(const float* __restrict__ dpartial, int ndp,
                                                       const float* __restrict__ partial, int ntiles,
                                                       float* __restrict__ out) {
    const int t = threadIdx.x;
    const int lane = t & 63, wave = t >> 6;
    __shared__ float sred[4];
    __shared__ float sred2[4];

    float dacc = (t < ndp) ? dpartial[t] : 0.0f;
#pragma unroll
    for (int off = 32; off >= 1; off >>= 1) dacc += __shfl_down(dacc, off, 64);
    if (lane == 0) sred[wave] = dacc;
    __syncthreads();
    const float denom = sqrtf(sred[0] + sred[1] + sred[2] + sred[3]);

    float lsum = 0.0f;
    if (t < BATCH) {
        float ss = 0.0f;
        for (int k = 0; k < ntiles; ++k) ss += partial[(size_t)t * ntiles + k];
        lsum = 2.0f * sqrtf(ss) / denom;
    }
#pragma unroll
    for (int off = 32; off >= 1; off >>= 1) lsum += __shfl_down(lsum, off, 64);
    if (lane == 0) sred2[wave] = lsum;
    __syncthreads();
    if (t == 0) out[0] = sred2[0] + sred2[1] + sred2[2] + sred2[3];
}

extern "C" void kernel_launch(void* const* d_in, const int* in_sizes, int n_in,
                              void* d_out, int out_size, void* d_ws, size_t ws_size,
                              hipStream_t stream) {
    const float* dv   = (const float*)d_in[0];   // [128,512,256] fp32
    const float* Smat = (const float*)d_in[1];   // [512,512] fp32
    float* out = (float*)d_out;

    const size_t st_bytes = (size_t)NS * NS * 4;          // 1 MB
    const size_t pt_bytes = (size_t)BATCH * NT * 4;       // 5 KB
    const size_t dp_bytes = 256 * 4;
    const size_t need = st_bytes + pt_bytes + dp_bytes;

    if (ws_size >= need) {
        char* w = (char*)d_ws;
        float* St      = (float*)w;   w += st_bytes;
        float* partial = (float*)w;   w += pt_bytes;
        float* dpart   = (float*)w;

        st_denom_kernel<<<dim3(256), 256, 0, stream>>>(Smat, St, dpart);
        gram_fused_kernel<<<dim3(NT * BATCH), 512, 0, stream>>>(dv, Smat, St, partial);
        finalize_kernel<<<dim3(1), 256, 0, stream>>>(dpart, 256, partial, NT, out);
    } else {
        float* n2      = (float*)d_ws;
        float* partial = n2 + (size_t)BATCH * NS;
        float* dpart   = partial + (size_t)BATCH * 16;

        norms_kernel<<<dim3(BATCH * NS / 4), 256, 0, stream>>>(dv, n2);
        denom_kernel<<<dim3(128), 256, 0, stream>>>(Smat, dpart);
        gram_f32_kernel<<<dim3(16, BATCH), 256, 0, stream>>>(dv, Smat, n2, partial);
        finalize_kernel<<<dim3(1), 256, 0, stream>>>(dpart, 128, partial, 16, out);
    }
}